// Round 9
// baseline (242.868 us; speedup 1.0000x reference)
//
#include <hip/hip_runtime.h>
#include <hip/hip_bf16.h>
#include <stdint.h>

// Problem constants
#define T_TOK 1024
#define DIN   2048
#define NOUT  8192   // 2*O
#define OSL   4096   // O per slice
#define ROWS_PAD 1408
#define BM 128
#define BN 128
#define BK 64        // two 32-k sub-tiles per barrier pair (kslim)

typedef _Float16 f16x8 __attribute__((ext_vector_type(8)));
typedef _Float16 f16x2 __attribute__((ext_vector_type(2)));
typedef float    f32x4 __attribute__((ext_vector_type(4)));

__device__ __forceinline__ void gload16(const void* gp, void* lp) {
  __builtin_amdgcn_global_load_lds(
      (__attribute__((address_space(1))) void*)gp,
      (__attribute__((address_space(3))) void*)lp, 16, 0, 0);
}

__device__ __forceinline__ f16x2 u2h(uint32_t u) {
  union { uint32_t u; f16x2 h; } c; c.u = u; return c.h;
}

__device__ __forceinline__ f16x8 cvt_interleave(float4 f0, float4 f1) {
  // k-order [0,4,1,5,2,6,3,7] so packed-nibble pairs (n_j, n_{j+4}) line up
  f16x8 h;
  h[0] = (_Float16)f0.x; h[1] = (_Float16)f1.x;
  h[2] = (_Float16)f0.y; h[3] = (_Float16)f1.y;
  h[4] = (_Float16)f0.z; h[5] = (_Float16)f1.z;
  h[6] = (_Float16)f0.w; h[7] = (_Float16)f1.w;
  return h;
}

// ================= kernel 1: sort + x->fp16 + W_eff build, one launch =================
// blocks: [0] sort | [1, 1+T_TOK+1) x rows (last = zero pad row) | rest: weff/wbh rows
template<bool FULL>
__global__ void prep_all(const float* __restrict__ x, const float* __restrict__ wb,
                         const int* __restrict__ qw0, const int* __restrict__ qw1,
                         const int* __restrict__ qz0, const int* __restrict__ qz1,
                         const float* __restrict__ sc0, const float* __restrict__ sc1,
                         const int* __restrict__ indices,
                         _Float16* __restrict__ xh,    // [T_TOK+1][DIN], row T_TOK = zeros
                         _Float16* __restrict__ wout,  // FULL: weff [4][NOUT][DIN]; else wbh [NOUT][DIN]
                         int* __restrict__ inv, int* __restrict__ meta)
{
  const int b = blockIdx.x;
  const int tid = threadIdx.x;

  if (b == 0) {  // ---- token sort into 128-aligned adapter groups ----
    __shared__ int cnt[4], cur[4];
    if (tid < 4) cnt[tid] = 0;
    __syncthreads();
    for (int t = tid; t < T_TOK; t += 256) atomicAdd(&cnt[indices[t]], 1);
    __syncthreads();
    if (tid == 0) {
      int off = 0;
      for (int a = 0; a < 4; ++a) {
        meta[a] = off;
        meta[5 + a] = off + cnt[a];
        cur[a] = off;
        off = (off + cnt[a] + 127) & ~127;
      }
      meta[4] = off;
    }
    __syncthreads();
    for (int i = tid; i < ROWS_PAD; i += 256) inv[i] = -1;
    __syncthreads();
    for (int t = tid; t < T_TOK; t += 256) {
      int a = indices[t];
      int p = atomicAdd(&cur[a], 1);
      inv[p] = t;
    }
    return;
  }

  if (b <= 1 + T_TOK) {  // ---- x -> fp16, natural order, interleaved ----
    const int row = b - 1;          // 0..T_TOK (T_TOK = zero row)
    const int d0 = tid * 8;
    f16x8 h;
    if (row < T_TOK) {
      const float* src = x + (size_t)row * DIN + d0;
      h = cvt_interleave(*(const float4*)src, *(const float4*)(src + 4));
    } else {
#pragma unroll
      for (int j = 0; j < 8; ++j) h[j] = (_Float16)0.0f;
    }
    *(f16x8*)(xh + (size_t)row * DIN + d0) = h;
    return;
  }

  // ---- W_eff (or plain fp16 Wb) row n ----
  const int n = b - (2 + T_TOK);    // 0..NOUT-1
  const int d0 = tid * 8;
  const float* src = wb + (size_t)n * DIN + d0;
  union { f16x8 v; f16x2 p[4]; } wbr;
  wbr.v = cvt_interleave(*(const float4*)src, *(const float4*)(src + 4));

  if (!FULL) {
    *(f16x8*)(wout + (size_t)n * DIN + d0) = wbr.v;
    return;
  }

  const int sl = n >> 12;
  const int n_sl = n & (OSL - 1);
  const int* qw = sl ? qw1 : qw0;
  const int* qz = sl ? qz1 : qz0;
  const float* sc = sl ? sc1 : sc0;

#pragma unroll
  for (int a = 0; a < 4; ++a) {
    const uint32_t wv = (uint32_t)qw[((size_t)(a * OSL + n_sl)) * (DIN / 8) + tid];
    const int zw = qz[a * (OSL / 8) + (n_sl >> 3)];
    const float s = sc[(size_t)a * OSL + n_sl];
    const int z = (zw >> ((n_sl & 7) << 2)) & 0xF;
    f16x2 s2; s2[0] = s2[1] = (_Float16)s;
    f16x2 k2; k2[0] = k2[1] = (_Float16)(float)(-(1024 + z));
    union { f16x8 v; f16x2 p[4]; } h;
#pragma unroll
    for (int j = 0; j < 4; ++j) {
      uint32_t t0 = ((wv >> (4 * j)) & 0x000F000Fu) | 0x64006400u;
      h.p[j] = (u2h(t0) + k2) * s2 + wbr.p[j];
    }
    *(f16x8*)(wout + ((size_t)(a * NOUT) + n) * DIN + d0) = h.v;
  }
}

// ================= kernel 2 (FULL): pure MFMA GEMM on W_eff, gather-A =================
// R0-verified 68us structure with ONE change: BK 32->64 (two 32-k sub-tiles per
// barrier pair), halving the per-K-step barrier-drain count that its profile
// (MfmaUtil 26.6, VALU 12, HBM 27, occ 24 -- all unsaturated) identified as the
// dominant fixed cost. All staging via global_load_lds with the same XOR chunk
// swizzle -> conflict-free ds_read_b128. LDS 32 KB single-buffered.
__global__ __launch_bounds__(256) void kslim(
    const _Float16* __restrict__ xh, const _Float16* __restrict__ weff,
    const float* __restrict__ bias,
    const int* __restrict__ inv, const int* __restrict__ meta,
    float* __restrict__ out)
{
  const int m0 = blockIdx.y * BM;
  if (m0 >= meta[4]) return;
  int ad = 0;
  if (m0 >= meta[1]) ad = 1;
  if (m0 >= meta[2]) ad = 2;
  if (m0 >= meta[3]) ad = 3;
  if (m0 >= meta[5 + ad]) return;      // tile entirely pad

  const int n0 = blockIdx.x * BN;
  const int tid  = threadIdx.x;
  const int wave = tid >> 6;
  const int lane = tid & 63;
  const int quad = lane >> 4;
  const int l16  = lane & 15;
  const int wm = (wave & 1) << 6;
  const int wn = (wave >> 1) << 6;

  // LDS: A sub0 [0,8K) | A sub1 [8K,16K) | B sub0 [16K,24K) | B sub1 [24K,32K)
  __shared__ __align__(16) char smem[32768];

  f32x4 acc[4][4];
#pragma unroll
  for (int i = 0; i < 4; ++i)
#pragma unroll
    for (int j = 0; j < 4; ++j) acc[i][j] = (f32x4)0.0f;

  // staged chunk position (tid&3) holds source chunk (tid&3)^((row>>1)&3)
  const int kch = (((tid & 3) ^ ((tid >> 3) & 3)) << 3);
  const int rloc = tid >> 2;
  int r0 = inv[m0 + rloc];       if (r0 < 0) r0 = T_TOK;   // pad -> zero row
  int r1 = inv[m0 + rloc + 64];  if (r1 < 0) r1 = T_TOK;
  const _Float16* ag0 = xh + (size_t)r0 * DIN + kch;
  const _Float16* ag1 = xh + (size_t)r1 * DIN + kch;
  const _Float16* bg0 = weff + ((size_t)(ad * NOUT) + n0 + rloc) * DIN + kch;
  const _Float16* bg1 = bg0 + (size_t)64 * DIN;
  char* sa0 = smem +          wave * 1024;
  char* sa1 = smem +   4096 + wave * 1024;
  char* sb0 = smem +  16384 + wave * 1024;
  char* sb1 = smem +  20480 + wave * 1024;

  const int qoff = ((quad ^ ((l16 >> 1) & 3)) << 4);

  for (int k0 = 0; k0 < DIN; k0 += BK) {
    // sub-tile 0 (k..k+31)
    gload16(ag0, sa0);
    gload16(ag1, sa1);
    gload16(bg0, sb0);
    gload16(bg1, sb1);
    // sub-tile 1 (k+32..k+63)
    gload16(ag0 + 32, sa0 + 8192);
    gload16(ag1 + 32, sa1 + 8192);
    gload16(bg0 + 32, sb0 + 8192);
    gload16(bg1 + 32, sb1 + 8192);
    __syncthreads();

#pragma unroll
    for (int sub = 0; sub < 2; ++sub) {
      f16x8 af[4], bfr[4];
#pragma unroll
      for (int t = 0; t < 4; ++t)
        af[t] = *(const f16x8*)(smem + sub * 8192 + (wm + t * 16 + l16) * 64 + qoff);
#pragma unroll
      for (int t = 0; t < 4; ++t)
        bfr[t] = *(const f16x8*)(smem + 16384 + sub * 8192 + (wn + t * 16 + l16) * 64 + qoff);
#pragma unroll
      for (int mt = 0; mt < 4; ++mt)
#pragma unroll
        for (int nt = 0; nt < 4; ++nt)
          acc[mt][nt] = __builtin_amdgcn_mfma_f32_16x16x32_f16(af[mt], bfr[nt], acc[mt][nt], 0, 0, 0);
    }
    __syncthreads();

    ag0 += BK; ag1 += BK; bg0 += BK; bg1 += BK;
  }

  // epilogue: C/D col=lane&15, row=quad*4+reg; scatter to out[token], +bias
#pragma unroll
  for (int mt = 0; mt < 4; ++mt) {
    const int rowb = m0 + wm + mt * 16 + quad * 4;
    int tk[4];
#pragma unroll
    for (int r = 0; r < 4; ++r) tk[r] = inv[rowb + r];
#pragma unroll
    for (int nt = 0; nt < 4; ++nt) {
      const int col = n0 + wn + nt * 16 + l16;
      const float bv = bias[col];
#pragma unroll
      for (int r = 0; r < 4; ++r) {
        if (tk[r] >= 0)
          out[(size_t)tk[r] * NOUT + col] = acc[mt][nt][r] + bv;
      }
    }
  }
}

// ================= kernel 2 (fallback, ws too small): in-loop dequant =================
__global__ __launch_bounds__(256) void kdq(
    const _Float16* __restrict__ xh, const _Float16* __restrict__ wbh,
    const int* __restrict__ qw0, const int* __restrict__ qw1,
    const int* __restrict__ qz0, const int* __restrict__ qz1,
    const float* __restrict__ sc0, const float* __restrict__ sc1,
    const float* __restrict__ bias,
    const int* __restrict__ inv, const int* __restrict__ meta,
    float* __restrict__ out)
{
  const int m0 = blockIdx.y * BM;
  if (m0 >= meta[4]) return;
  int ad = 0;
  if (m0 >= meta[1]) ad = 1;
  if (m0 >= meta[2]) ad = 2;
  if (m0 >= meta[3]) ad = 3;
  if (m0 >= meta[5 + ad]) return;

  const int n0 = blockIdx.x * BN;
  const int sl = n0 >> 12;
  const int tid  = threadIdx.x;
  const int wave = tid >> 6;
  const int lane = tid & 63;
  const int quad = lane >> 4;
  const int l16  = lane & 15;
  const int wm = (wave & 1) << 6;
  const int wn = (wave >> 1) << 6;

  __shared__ __align__(16) char smem[16384];

  f32x4 acc[4][4];
#pragma unroll
  for (int i = 0; i < 4; ++i)
#pragma unroll
    for (int j = 0; j < 4; ++j) acc[i][j] = (f32x4)0.0f;

  const int kch = (((tid & 3) ^ ((tid >> 3) & 3)) << 3);
  const int rloc = tid >> 2;
  int r0 = inv[m0 + rloc];       if (r0 < 0) r0 = T_TOK;
  int r1 = inv[m0 + rloc + 64];  if (r1 < 0) r1 = T_TOK;
  const _Float16* ag0 = xh + (size_t)r0 * DIN + kch;
  const _Float16* ag1 = xh + (size_t)r1 * DIN + kch;
  char* sa0 = smem + wave * 1024;
  char* sa1 = smem + 4096 + wave * 1024;

  const int o_local = tid >> 1;
  const int o = n0 + o_local;
  const int o_sl = o & (OSL - 1);
  const int* qw = (sl ? qw1 : qw0) + ((size_t)ad * OSL + o_sl) * (DIN / 8) + ((tid & 1) << 1);
  const int zw = (sl ? qz1 : qz0)[ad * (OSL / 8) + (o_sl >> 3)];
  const float s = (sl ? sc1 : sc0)[(size_t)ad * OSL + o_sl];
  const int z = (zw >> ((o_sl & 7) << 2)) & 0xF;
  f16x2 s2; s2[0] = s2[1] = (_Float16)s;
  f16x2 k2; k2[0] = k2[1] = (_Float16)(float)(-(1024 + z));
  const _Float16* wbhp = wbh + (size_t)o * DIN + ((tid & 1) << 4);

  const int bswz = (o_local >> 1) & 3;
  char* bb = smem + 8192 + o_local * 64;
  char* bw0 = bb + (((((tid & 1) << 1)    ) ^ bswz) << 4);
  char* bw1 = bb + (((((tid & 1) << 1) | 1) ^ bswz) << 4);
  const int qoff = ((quad ^ ((l16 >> 1) & 3)) << 4);

  for (int k0 = 0; k0 < DIN; k0 += 32) {
    gload16(ag0, sa0);
    gload16(ag1, sa1);
    int2 wv = *(const int2*)qw;
    union { f16x8 v; f16x2 p[4]; } wA, wB;
    wA.v = *(const f16x8*)wbhp;
    wB.v = *(const f16x8*)(wbhp + 8);
    const uint32_t wx = (uint32_t)wv.x, wy = (uint32_t)wv.y;
    union { f16x8 v; f16x2 p[4]; } h0, h1;
#pragma unroll
    for (int j = 0; j < 4; ++j) {
      uint32_t t0 = ((wx >> (4 * j)) & 0x000F000Fu) | 0x64006400u;
      uint32_t t1 = ((wy >> (4 * j)) & 0x000F000Fu) | 0x64006400u;
      h0.p[j] = (u2h(t0) + k2) * s2 + wA.p[j];
      h1.p[j] = (u2h(t1) + k2) * s2 + wB.p[j];
    }
    *(f16x8*)bw0 = h0.v;
    *(f16x8*)bw1 = h1.v;
    __syncthreads();

    f16x8 af[4], bfr[4];
#pragma unroll
    for (int t = 0; t < 4; ++t)
      af[t] = *(const f16x8*)(smem + (wm + t * 16 + l16) * 64 + qoff);
#pragma unroll
    for (int t = 0; t < 4; ++t)
      bfr[t] = *(const f16x8*)(smem + 8192 + (wn + t * 16 + l16) * 64 + qoff);
#pragma unroll
    for (int mt = 0; mt < 4; ++mt)
#pragma unroll
      for (int nt = 0; nt < 4; ++nt)
        acc[mt][nt] = __builtin_amdgcn_mfma_f32_16x16x32_f16(af[mt], bfr[nt], acc[mt][nt], 0, 0, 0);
    __syncthreads();

    ag0 += 32; ag1 += 32; qw += 4; wbhp += 32;
  }

#pragma unroll
  for (int mt = 0; mt < 4; ++mt) {
    const int rowb = m0 + wm + mt * 16 + quad * 4;
    int tk[4];
#pragma unroll
    for (int r = 0; r < 4; ++r) tk[r] = inv[rowb + r];
#pragma unroll
    for (int nt = 0; nt < 4; ++nt) {
      const int col = n0 + wn + nt * 16 + l16;
      const float bv = bias[col];
#pragma unroll
      for (int r = 0; r < 4; ++r) {
        if (tk[r] >= 0)
          out[(size_t)tk[r] * NOUT + col] = acc[mt][nt][r] + bv;
      }
    }
  }
}

extern "C" void kernel_launch(void* const* d_in, const int* in_sizes, int n_in,
                              void* d_out, int out_size, void* d_ws, size_t ws_size,
                              hipStream_t stream) {
  const float* x    = (const float*)d_in[0];
  const float* wb   = (const float*)d_in[1];
  const float* bias = (const float*)d_in[2];
  const int*   qw0  = (const int*)d_in[3];
  const int*   qw1  = (const int*)d_in[4];
  const int*   qz0  = (const int*)d_in[5];
  const int*   qz1  = (const int*)d_in[6];
  const float* sc0  = (const float*)d_in[7];
  const float* sc1  = (const float*)d_in[8];
  const int*   indices = (const int*)d_in[11];
  float* out = (float*)d_out;

  // workspace: xh [(T_TOK+1)*DIN f16] | inv | meta | weff (128 MB) or wbh (32 MB)
  char* w = (char*)d_ws;
  _Float16* xh = (_Float16*)w;
  size_t off = (size_t)(T_TOK + 1) * DIN * 2;
  int* inv  = (int*)(w + off);
  int* meta = inv + ROWS_PAD;
  size_t woff = (off + (size_t)ROWS_PAD * 4 + 64 + 255) & ~(size_t)255;
  _Float16* wout = (_Float16*)(w + woff);
  const bool full = ws_size >= woff + (size_t)4 * NOUT * DIN * 2;

  const int nprep = 2 + T_TOK + NOUT;   // sort + x rows (+zero) + weight rows
  dim3 g(NOUT / BN, ROWS_PAD / BM, 1);  // 64 x 11

  if (full) {
    prep_all<true><<<nprep, 256, 0, stream>>>(x, wb, qw0, qw1, qz0, qz1, sc0, sc1,
                                              indices, xh, wout, inv, meta);
    kslim<<<g, 256, 0, stream>>>(xh, wout, bias, inv, meta, out);
  } else {
    prep_all<false><<<nprep, 256, 0, stream>>>(x, wb, qw0, qw1, qz0, qz1, sc0, sc1,
                                               indices, xh, wout, inv, meta);
    kdq<<<g, 256, 0, stream>>>(xh, wout, qw0, qw1, qz0, qz1, sc0, sc1,
                               bias, inv, meta, out);
  }
}

// Round 10
// 239.164 us; speedup vs baseline: 1.0155x; 1.0155x over previous
//
#include <hip/hip_runtime.h>
#include <hip/hip_bf16.h>
#include <stdint.h>

// Problem constants
#define T_TOK 1024
#define DIN   2048
#define NOUT  8192   // 2*O
#define OSL   4096   // O per slice
#define ROWS_PAD 1408
#define BM 128
#define BN 128
#define BK 32
#define NT (DIN / BK)   // 64 K-steps
#define BUFS 16384      // second LDS buffer base (per-buf: A [0,8K), B [8K,16K))

typedef _Float16 f16x8 __attribute__((ext_vector_type(8)));
typedef _Float16 f16x2 __attribute__((ext_vector_type(2)));
typedef float    f32x4 __attribute__((ext_vector_type(4)));

__device__ __forceinline__ void gload16(const void* gp, void* lp) {
  __builtin_amdgcn_global_load_lds(
      (__attribute__((address_space(1))) void*)gp,
      (__attribute__((address_space(3))) void*)lp, 16, 0, 0);
}

__device__ __forceinline__ f16x2 u2h(uint32_t u) {
  union { uint32_t u; f16x2 h; } c; c.u = u; return c.h;
}

__device__ __forceinline__ f16x8 cvt_interleave(float4 f0, float4 f1) {
  // k-order [0,4,1,5,2,6,3,7] so packed-nibble pairs (n_j, n_{j+4}) line up
  f16x8 h;
  h[0] = (_Float16)f0.x; h[1] = (_Float16)f1.x;
  h[2] = (_Float16)f0.y; h[3] = (_Float16)f1.y;
  h[4] = (_Float16)f0.z; h[5] = (_Float16)f1.z;
  h[6] = (_Float16)f0.w; h[7] = (_Float16)f1.w;
  return h;
}

// ================= kernel 1: sort + x->fp16 + W_eff build, one launch =================
// blocks: [0] sort | [1, 1+T_TOK+1) x rows (last = zero pad row) | rest: weff/wbh rows
template<bool FULL>
__global__ void prep_all(const float* __restrict__ x, const float* __restrict__ wb,
                         const int* __restrict__ qw0, const int* __restrict__ qw1,
                         const int* __restrict__ qz0, const int* __restrict__ qz1,
                         const float* __restrict__ sc0, const float* __restrict__ sc1,
                         const int* __restrict__ indices,
                         _Float16* __restrict__ xh,    // [T_TOK+1][DIN], row T_TOK = zeros
                         _Float16* __restrict__ wout,  // FULL: weff [4][NOUT][DIN]; else wbh [NOUT][DIN]
                         int* __restrict__ inv, int* __restrict__ meta)
{
  const int b = blockIdx.x;
  const int tid = threadIdx.x;

  if (b == 0) {  // ---- token sort into 128-aligned adapter groups ----
    __shared__ int cnt[4], cur[4];
    if (tid < 4) cnt[tid] = 0;
    __syncthreads();
    for (int t = tid; t < T_TOK; t += 256) atomicAdd(&cnt[indices[t]], 1);
    __syncthreads();
    if (tid == 0) {
      int off = 0;
      for (int a = 0; a < 4; ++a) {
        meta[a] = off;
        meta[5 + a] = off + cnt[a];
        cur[a] = off;
        off = (off + cnt[a] + 127) & ~127;
      }
      meta[4] = off;
    }
    __syncthreads();
    for (int i = tid; i < ROWS_PAD; i += 256) inv[i] = -1;
    __syncthreads();
    for (int t = tid; t < T_TOK; t += 256) {
      int a = indices[t];
      int p = atomicAdd(&cur[a], 1);
      inv[p] = t;
    }
    return;
  }

  if (b <= 1 + T_TOK) {  // ---- x -> fp16, natural order, interleaved ----
    const int row = b - 1;          // 0..T_TOK (T_TOK = zero row)
    const int d0 = tid * 8;
    f16x8 h;
    if (row < T_TOK) {
      const float* src = x + (size_t)row * DIN + d0;
      h = cvt_interleave(*(const float4*)src, *(const float4*)(src + 4));
    } else {
#pragma unroll
      for (int j = 0; j < 8; ++j) h[j] = (_Float16)0.0f;
    }
    *(f16x8*)(xh + (size_t)row * DIN + d0) = h;
    return;
  }

  // ---- W_eff (or plain fp16 Wb) row n ----
  const int n = b - (2 + T_TOK);    // 0..NOUT-1
  const int d0 = tid * 8;
  const float* src = wb + (size_t)n * DIN + d0;
  union { f16x8 v; f16x2 p[4]; } wbr;
  wbr.v = cvt_interleave(*(const float4*)src, *(const float4*)(src + 4));

  if (!FULL) {
    *(f16x8*)(wout + (size_t)n * DIN + d0) = wbr.v;
    return;
  }

  const int sl = n >> 12;
  const int n_sl = n & (OSL - 1);
  const int* qw = sl ? qw1 : qw0;
  const int* qz = sl ? qz1 : qz0;
  const float* sc = sl ? sc1 : sc0;

#pragma unroll
  for (int a = 0; a < 4; ++a) {
    const uint32_t wv = (uint32_t)qw[((size_t)(a * OSL + n_sl)) * (DIN / 8) + tid];
    const int zw = qz[a * (OSL / 8) + (n_sl >> 3)];
    const float s = sc[(size_t)a * OSL + n_sl];
    const int z = (zw >> ((n_sl & 7) << 2)) & 0xF;
    f16x2 s2; s2[0] = s2[1] = (_Float16)s;
    f16x2 k2; k2[0] = k2[1] = (_Float16)(float)(-(1024 + z));
    union { f16x8 v; f16x2 p[4]; } h;
#pragma unroll
    for (int j = 0; j < 4; ++j) {
      uint32_t t0 = ((wv >> (4 * j)) & 0x000F000Fu) | 0x64006400u;
      h.p[j] = (u2h(t0) + k2) * s2 + wbr.p[j];
    }
    *(f16x8*)(wout + ((size_t)(a * NOUT) + n) * DIN + d0) = h.v;
  }
}

// ================= kernel 2 (FULL): pure MFMA GEMM on W_eff, gather-A =================
// R0-verified 68us kernel with ONE structural change: LDS double-buffer + ONE
// __syncthreads per K-step (T3 minimum 2-phase). stage(t+1 -> buf^1) is issued
// BEFORE compute(t -> buf), so tile t's 8 ds_read + 16 MFMA run while tile
// t+1's 4 global_load_lds are in flight; the single end-of-step barrier drain
// pays only the residual latency. Barrier count halves (128 -> 64). All
// layouts/swizzles byte-identical to R0. 2x-unrolled, static buffer addressing.
__global__ __launch_bounds__(256) void kslim(
    const _Float16* __restrict__ xh, const _Float16* __restrict__ weff,
    const float* __restrict__ bias,
    const int* __restrict__ inv, const int* __restrict__ meta,
    float* __restrict__ out)
{
  const int m0 = blockIdx.y * BM;
  if (m0 >= meta[4]) return;
  int ad = 0;
  if (m0 >= meta[1]) ad = 1;
  if (m0 >= meta[2]) ad = 2;
  if (m0 >= meta[3]) ad = 3;
  if (m0 >= meta[5 + ad]) return;      // tile entirely pad

  const int n0 = blockIdx.x * BN;
  const int tid  = threadIdx.x;
  const int wave = tid >> 6;
  const int lane = tid & 63;
  const int quad = lane >> 4;
  const int l16  = lane & 15;
  const int wm = (wave & 1) << 6;
  const int wn = (wave >> 1) << 6;

  // buf0 [0,16K): A [0,8K) B [8K,16K) | buf1 [16K,32K): same layout
  __shared__ __align__(16) char smem[32768];

  f32x4 acc[4][4];
#pragma unroll
  for (int i = 0; i < 4; ++i)
#pragma unroll
    for (int j = 0; j < 4; ++j) acc[i][j] = (f32x4)0.0f;

  // staged chunk position (tid&3) holds source chunk (tid&3)^((row>>1)&3)
  const int kch = (((tid & 3) ^ ((tid >> 3) & 3)) << 3);
  const int rloc = tid >> 2;
  int r0 = inv[m0 + rloc];       if (r0 < 0) r0 = T_TOK;   // pad -> zero row
  int r1 = inv[m0 + rloc + 64];  if (r1 < 0) r1 = T_TOK;
  const _Float16* ag0 = xh + (size_t)r0 * DIN + kch;
  const _Float16* ag1 = xh + (size_t)r1 * DIN + kch;
  const _Float16* bg0 = weff + ((size_t)(ad * NOUT) + n0 + rloc) * DIN + kch;
  const _Float16* bg1 = bg0 + (size_t)64 * DIN;
  const int saoff0 =        wave * 1024;
  const int saoff1 = 4096 + wave * 1024;
  const int sboff0 = 8192 + wave * 1024;
  const int sboff1 = 12288 + wave * 1024;

  const int qoff = ((quad ^ ((l16 >> 1) & 3)) << 4);

  // STAGE(t, base): 4 global_load_lds of the t-th 32-k slab into buffer 'base'
#define STAGE(t, base)                                         \
  do {                                                         \
    gload16(ag0 + (size_t)(t) * BK, smem + (base) + saoff0);   \
    gload16(ag1 + (size_t)(t) * BK, smem + (base) + saoff1);   \
    gload16(bg0 + (size_t)(t) * BK, smem + (base) + sboff0);   \
    gload16(bg1 + (size_t)(t) * BK, smem + (base) + sboff1);   \
  } while (0)

#define MFMASTEP(base)                                                        \
  do {                                                                        \
    f16x8 af[4], bfr[4];                                                      \
    _Pragma("unroll")                                                         \
    for (int tt = 0; tt < 4; ++tt)                                            \
      af[tt] = *(const f16x8*)(smem + (base) + (wm + tt * 16 + l16) * 64 + qoff); \
    _Pragma("unroll")                                                         \
    for (int tt = 0; tt < 4; ++tt)                                            \
      bfr[tt] = *(const f16x8*)(smem + (base) + 8192 + (wn + tt * 16 + l16) * 64 + qoff); \
    _Pragma("unroll")                                                         \
    for (int mt = 0; mt < 4; ++mt)                                            \
      _Pragma("unroll")                                                       \
      for (int nt = 0; nt < 4; ++nt)                                          \
        acc[mt][nt] = __builtin_amdgcn_mfma_f32_16x16x32_f16(af[mt], bfr[nt], acc[mt][nt], 0, 0, 0); \
  } while (0)

  // prologue: tile 0 -> buf0
  STAGE(0, 0);
  __syncthreads();

  // main: pairs (t even): stage t+1->buf1 | compute t (buf0) | barrier
  //                       stage t+2->buf0 | compute t+1 (buf1) | barrier
  for (int t = 0; t < NT - 2; t += 2) {      // t = 0..60: covers tiles 0..61
    STAGE(t + 1, BUFS);
    MFMASTEP(0);
    __syncthreads();
    STAGE(t + 2, 0);
    MFMASTEP(BUFS);
    __syncthreads();
  }
  // tail: buf0 = tile 62
  STAGE(NT - 1, BUFS);
  MFMASTEP(0);                               // tile 62
  __syncthreads();
  MFMASTEP(BUFS);                            // tile 63

#undef STAGE
#undef MFMASTEP

  // epilogue: C/D col=lane&15, row=quad*4+reg; scatter to out[token], +bias
#pragma unroll
  for (int mt = 0; mt < 4; ++mt) {
    const int rowb = m0 + wm + mt * 16 + quad * 4;
    int tk[4];
#pragma unroll
    for (int r = 0; r < 4; ++r) tk[r] = inv[rowb + r];
#pragma unroll
    for (int nt = 0; nt < 4; ++nt) {
      const int col = n0 + wn + nt * 16 + l16;
      const float bv = bias[col];
#pragma unroll
      for (int r = 0; r < 4; ++r) {
        if (tk[r] >= 0)
          out[(size_t)tk[r] * NOUT + col] = acc[mt][nt][r] + bv;
      }
    }
  }
}

// ================= kernel 2 (fallback, ws too small): in-loop dequant =================
__global__ __launch_bounds__(256) void kdq(
    const _Float16* __restrict__ xh, const _Float16* __restrict__ wbh,
    const int* __restrict__ qw0, const int* __restrict__ qw1,
    const int* __restrict__ qz0, const int* __restrict__ qz1,
    const float* __restrict__ sc0, const float* __restrict__ sc1,
    const float* __restrict__ bias,
    const int* __restrict__ inv, const int* __restrict__ meta,
    float* __restrict__ out)
{
  const int m0 = blockIdx.y * BM;
  if (m0 >= meta[4]) return;
  int ad = 0;
  if (m0 >= meta[1]) ad = 1;
  if (m0 >= meta[2]) ad = 2;
  if (m0 >= meta[3]) ad = 3;
  if (m0 >= meta[5 + ad]) return;

  const int n0 = blockIdx.x * BN;
  const int sl = n0 >> 12;
  const int tid  = threadIdx.x;
  const int wave = tid >> 6;
  const int lane = tid & 63;
  const int quad = lane >> 4;
  const int l16  = lane & 15;
  const int wm = (wave & 1) << 6;
  const int wn = (wave >> 1) << 6;

  __shared__ __align__(16) char smem[16384];

  f32x4 acc[4][4];
#pragma unroll
  for (int i = 0; i < 4; ++i)
#pragma unroll
    for (int j = 0; j < 4; ++j) acc[i][j] = (f32x4)0.0f;

  const int kch = (((tid & 3) ^ ((tid >> 3) & 3)) << 3);
  const int rloc = tid >> 2;
  int r0 = inv[m0 + rloc];       if (r0 < 0) r0 = T_TOK;
  int r1 = inv[m0 + rloc + 64];  if (r1 < 0) r1 = T_TOK;
  const _Float16* ag0 = xh + (size_t)r0 * DIN + kch;
  const _Float16* ag1 = xh + (size_t)r1 * DIN + kch;
  char* sa0 = smem + wave * 1024;
  char* sa1 = smem + 4096 + wave * 1024;

  const int o_local = tid >> 1;
  const int o = n0 + o_local;
  const int o_sl = o & (OSL - 1);
  const int* qw = (sl ? qw1 : qw0) + ((size_t)ad * OSL + o_sl) * (DIN / 8) + ((tid & 1) << 1);
  const int zw = (sl ? qz1 : qz0)[ad * (OSL / 8) + (o_sl >> 3)];
  const float s = (sl ? sc1 : sc0)[(size_t)ad * OSL + o_sl];
  const int z = (zw >> ((o_sl & 7) << 2)) & 0xF;
  f16x2 s2; s2[0] = s2[1] = (_Float16)s;
  f16x2 k2; k2[0] = k2[1] = (_Float16)(float)(-(1024 + z));
  const _Float16* wbhp = wbh + (size_t)o * DIN + ((tid & 1) << 4);

  const int bswz = (o_local >> 1) & 3;
  char* bb = smem + 8192 + o_local * 64;
  char* bw0 = bb + (((((tid & 1) << 1)    ) ^ bswz) << 4);
  char* bw1 = bb + (((((tid & 1) << 1) | 1) ^ bswz) << 4);
  const int qoff = ((quad ^ ((l16 >> 1) & 3)) << 4);

  for (int k0 = 0; k0 < DIN; k0 += 32) {
    gload16(ag0, sa0);
    gload16(ag1, sa1);
    int2 wv = *(const int2*)qw;
    union { f16x8 v; f16x2 p[4]; } wA, wB;
    wA.v = *(const f16x8*)wbhp;
    wB.v = *(const f16x8*)(wbhp + 8);
    const uint32_t wx = (uint32_t)wv.x, wy = (uint32_t)wv.y;
    union { f16x8 v; f16x2 p[4]; } h0, h1;
#pragma unroll
    for (int j = 0; j < 4; ++j) {
      uint32_t t0 = ((wx >> (4 * j)) & 0x000F000Fu) | 0x64006400u;
      uint32_t t1 = ((wy >> (4 * j)) & 0x000F000Fu) | 0x64006400u;
      h0.p[j] = (u2h(t0) + k2) * s2 + wA.p[j];
      h1.p[j] = (u2h(t1) + k2) * s2 + wB.p[j];
    }
    *(f16x8*)bw0 = h0.v;
    *(f16x8*)bw1 = h1.v;
    __syncthreads();

    f16x8 af[4], bfr[4];
#pragma unroll
    for (int t = 0; t < 4; ++t)
      af[t] = *(const f16x8*)(smem + (wm + t * 16 + l16) * 64 + qoff);
#pragma unroll
    for (int t = 0; t < 4; ++t)
      bfr[t] = *(const f16x8*)(smem + 8192 + (wn + t * 16 + l16) * 64 + qoff);
#pragma unroll
    for (int mt = 0; mt < 4; ++mt)
#pragma unroll
      for (int nt = 0; nt < 4; ++nt)
        acc[mt][nt] = __builtin_amdgcn_mfma_f32_16x16x32_f16(af[mt], bfr[nt], acc[mt][nt], 0, 0, 0);
    __syncthreads();

    ag0 += 32; ag1 += 32; qw += 4; wbhp += 32;
  }

#pragma unroll
  for (int mt = 0; mt < 4; ++mt) {
    const int rowb = m0 + wm + mt * 16 + quad * 4;
    int tk[4];
#pragma unroll
    for (int r = 0; r < 4; ++r) tk[r] = inv[rowb + r];
#pragma unroll
    for (int nt = 0; nt < 4; ++nt) {
      const int col = n0 + wn + nt * 16 + l16;
      const float bv = bias[col];
#pragma unroll
      for (int r = 0; r < 4; ++r) {
        if (tk[r] >= 0)
          out[(size_t)tk[r] * NOUT + col] = acc[mt][nt][r] + bv;
      }
    }
  }
}

extern "C" void kernel_launch(void* const* d_in, const int* in_sizes, int n_in,
                              void* d_out, int out_size, void* d_ws, size_t ws_size,
                              hipStream_t stream) {
  const float* x    = (const float*)d_in[0];
  const float* wb   = (const float*)d_in[1];
  const float* bias = (const float*)d_in[2];
  const int*   qw0  = (const int*)d_in[3];
  const int*   qw1  = (const int*)d_in[4];
  const int*   qz0  = (const int*)d_in[5];
  const int*   qz1  = (const int*)d_in[6];
  const float* sc0  = (const float*)d_in[7];
  const float* sc1  = (const float*)d_in[8];
  const int*   indices = (const int*)d_in[11];
  float* out = (float*)d_out;

  // workspace: xh [(T_TOK+1)*DIN f16] | inv | meta | weff (128 MB) or wbh (32 MB)
  char* w = (char*)d_ws;
  _Float16* xh = (_Float16*)w;
  size_t off = (size_t)(T_TOK + 1) * DIN * 2;
  int* inv  = (int*)(w + off);
  int* meta = inv + ROWS_PAD;
  size_t woff = (off + (size_t)ROWS_PAD * 4 + 64 + 255) & ~(size_t)255;
  _Float16* wout = (_Float16*)(w + woff);
  const bool full = ws_size >= woff + (size_t)4 * NOUT * DIN * 2;

  const int nprep = 2 + T_TOK + NOUT;   // sort + x rows (+zero) + weight rows
  dim3 g(NOUT / BN, ROWS_PAD / BM, 1);  // 64 x 11

  if (full) {
    prep_all<true><<<nprep, 256, 0, stream>>>(x, wb, qw0, qw1, qz0, qz1, sc0, sc1,
                                              indices, xh, wout, inv, meta);
    kslim<<<g, 256, 0, stream>>>(xh, wout, bias, inv, meta, out);
  } else {
    prep_all<false><<<nprep, 256, 0, stream>>>(x, wb, qw0, qw1, qz0, qz1, sc0, sc1,
                                               indices, xh, wout, inv, meta);
    kdq<<<g, 256, 0, stream>>>(xh, wout, qw0, qw1, qz0, qz1, sc0, sc1,
                               bias, inv, meta, out);
  }
}

// Round 11
// 228.171 us; speedup vs baseline: 1.0644x; 1.0482x over previous
//
#include <hip/hip_runtime.h>
#include <hip/hip_bf16.h>
#include <stdint.h>

// Problem constants
#define T_TOK 1024
#define DIN   2048
#define NOUT  8192   // 2*O
#define OSL   4096   // O per slice
#define ROWS_PAD 1408
#define BM 128
#define BN 128
#define BK 32

typedef _Float16 f16x8 __attribute__((ext_vector_type(8)));
typedef _Float16 f16x2 __attribute__((ext_vector_type(2)));
typedef float    f32x4 __attribute__((ext_vector_type(4)));

__device__ __forceinline__ void gload16(const void* gp, void* lp) {
  __builtin_amdgcn_global_load_lds(
      (__attribute__((address_space(1))) void*)gp,
      (__attribute__((address_space(3))) void*)lp, 16, 0, 0);
}

__device__ __forceinline__ f16x2 u2h(uint32_t u) {
  union { uint32_t u; f16x2 h; } c; c.u = u; return c.h;
}

__device__ __forceinline__ f16x8 cvt_interleave(float4 f0, float4 f1) {
  // k-order [0,4,1,5,2,6,3,7] so packed-nibble pairs (n_j, n_{j+4}) line up
  f16x8 h;
  h[0] = (_Float16)f0.x; h[1] = (_Float16)f1.x;
  h[2] = (_Float16)f0.y; h[3] = (_Float16)f1.y;
  h[4] = (_Float16)f0.z; h[5] = (_Float16)f1.z;
  h[6] = (_Float16)f0.w; h[7] = (_Float16)f1.w;
  return h;
}

// ================= kernel 1: sort + x->fp16 + W_eff build, one launch =================
// blocks: [0] sort | [1, 1+T_TOK+1) x rows (last = zero pad row) | rest: weff/wbh rows
template<bool FULL>
__global__ void prep_all(const float* __restrict__ x, const float* __restrict__ wb,
                         const int* __restrict__ qw0, const int* __restrict__ qw1,
                         const int* __restrict__ qz0, const int* __restrict__ qz1,
                         const float* __restrict__ sc0, const float* __restrict__ sc1,
                         const int* __restrict__ indices,
                         _Float16* __restrict__ xh,    // [T_TOK+1][DIN], row T_TOK = zeros
                         _Float16* __restrict__ wout,  // FULL: weff [4][NOUT][DIN]; else wbh [NOUT][DIN]
                         int* __restrict__ inv, int* __restrict__ meta)
{
  const int b = blockIdx.x;
  const int tid = threadIdx.x;

  if (b == 0) {  // ---- token sort into 128-aligned adapter groups ----
    __shared__ int cnt[4], cur[4];
    if (tid < 4) cnt[tid] = 0;
    __syncthreads();
    for (int t = tid; t < T_TOK; t += 256) atomicAdd(&cnt[indices[t]], 1);
    __syncthreads();
    if (tid == 0) {
      int off = 0;
      for (int a = 0; a < 4; ++a) {
        meta[a] = off;
        meta[5 + a] = off + cnt[a];
        cur[a] = off;
        off = (off + cnt[a] + 127) & ~127;
      }
      meta[4] = off;
    }
    __syncthreads();
    for (int i = tid; i < ROWS_PAD; i += 256) inv[i] = -1;
    __syncthreads();
    for (int t = tid; t < T_TOK; t += 256) {
      int a = indices[t];
      int p = atomicAdd(&cur[a], 1);
      inv[p] = t;
    }
    return;
  }

  if (b <= 1 + T_TOK) {  // ---- x -> fp16, natural order, interleaved ----
    const int row = b - 1;          // 0..T_TOK (T_TOK = zero row)
    const int d0 = tid * 8;
    f16x8 h;
    if (row < T_TOK) {
      const float* src = x + (size_t)row * DIN + d0;
      h = cvt_interleave(*(const float4*)src, *(const float4*)(src + 4));
    } else {
#pragma unroll
      for (int j = 0; j < 8; ++j) h[j] = (_Float16)0.0f;
    }
    *(f16x8*)(xh + (size_t)row * DIN + d0) = h;
    return;
  }

  // ---- W_eff (or plain fp16 Wb) row n ----
  const int n = b - (2 + T_TOK);    // 0..NOUT-1
  const int d0 = tid * 8;
  const float* src = wb + (size_t)n * DIN + d0;
  union { f16x8 v; f16x2 p[4]; } wbr;
  wbr.v = cvt_interleave(*(const float4*)src, *(const float4*)(src + 4));

  if (!FULL) {
    *(f16x8*)(wout + (size_t)n * DIN + d0) = wbr.v;
    return;
  }

  const int sl = n >> 12;
  const int n_sl = n & (OSL - 1);
  const int* qw = sl ? qw1 : qw0;
  const int* qz = sl ? qz1 : qz0;
  const float* sc = sl ? sc1 : sc0;

#pragma unroll
  for (int a = 0; a < 4; ++a) {
    const uint32_t wv = (uint32_t)qw[((size_t)(a * OSL + n_sl)) * (DIN / 8) + tid];
    const int zw = qz[a * (OSL / 8) + (n_sl >> 3)];
    const float s = sc[(size_t)a * OSL + n_sl];
    const int z = (zw >> ((n_sl & 7) << 2)) & 0xF;
    f16x2 s2; s2[0] = s2[1] = (_Float16)s;
    f16x2 k2; k2[0] = k2[1] = (_Float16)(float)(-(1024 + z));
    union { f16x8 v; f16x2 p[4]; } h;
#pragma unroll
    for (int j = 0; j < 4; ++j) {
      uint32_t t0 = ((wv >> (4 * j)) & 0x000F000Fu) | 0x64006400u;
      h.p[j] = (u2h(t0) + k2) * s2 + wbr.p[j];
    }
    *(f16x8*)(wout + ((size_t)(a * NOUT) + n) * DIN + d0) = h.v;
  }
}

// ================= kernel 2 (FULL): pure MFMA GEMM on W_eff, gather-A =================
// 128x128 tile, BK=32, 4 waves (2x2 of 64x64), 16x16x32 f16 MFMA, all staging via
// global_load_lds with XOR chunk swizzle -> conflict-free ds_read_b128.
// NOTE (session ledger): this simple 2-barrier compiler-scheduled loop is the
// measured optimum. Regressions measured: hand vmcnt/sched_barrier (R1/R2),
// in-loop dequant (R3), BN=64 TLP (R7), BK=64 (R9), dbuf+1-barrier (R10).
__global__ __launch_bounds__(256) void kslim(
    const _Float16* __restrict__ xh, const _Float16* __restrict__ weff,
    const float* __restrict__ bias,
    const int* __restrict__ inv, const int* __restrict__ meta,
    float* __restrict__ out)
{
  const int m0 = blockIdx.y * BM;
  if (m0 >= meta[4]) return;
  int ad = 0;
  if (m0 >= meta[1]) ad = 1;
  if (m0 >= meta[2]) ad = 2;
  if (m0 >= meta[3]) ad = 3;
  if (m0 >= meta[5 + ad]) return;      // tile entirely pad

  const int n0 = blockIdx.x * BN;
  const int tid  = threadIdx.x;
  const int wave = tid >> 6;
  const int lane = tid & 63;
  const int quad = lane >> 4;
  const int l16  = lane & 15;
  const int wm = (wave & 1) << 6;
  const int wn = (wave >> 1) << 6;

  __shared__ __align__(16) char smem[16384];  // A [0,8K), B [8K,16K)

  f32x4 acc[4][4];
#pragma unroll
  for (int i = 0; i < 4; ++i)
#pragma unroll
    for (int j = 0; j < 4; ++j) acc[i][j] = (f32x4)0.0f;

  // staged chunk position (tid&3) holds source chunk (tid&3)^((row>>1)&3)
  const int kch = (((tid & 3) ^ ((tid >> 3) & 3)) << 3);
  const int rloc = tid >> 2;
  int r0 = inv[m0 + rloc];       if (r0 < 0) r0 = T_TOK;   // pad -> zero row
  int r1 = inv[m0 + rloc + 64];  if (r1 < 0) r1 = T_TOK;
  const _Float16* ag0 = xh + (size_t)r0 * DIN + kch;
  const _Float16* ag1 = xh + (size_t)r1 * DIN + kch;
  const _Float16* bg0 = weff + ((size_t)(ad * NOUT) + n0 + rloc) * DIN + kch;
  const _Float16* bg1 = bg0 + (size_t)64 * DIN;
  char* sa0 = smem +         wave * 1024;
  char* sa1 = smem +  4096 + wave * 1024;
  char* sb0 = smem +  8192 + wave * 1024;
  char* sb1 = smem + 12288 + wave * 1024;

  const int qoff = ((quad ^ ((l16 >> 1) & 3)) << 4);

  for (int k0 = 0; k0 < DIN; k0 += BK) {
    gload16(ag0, sa0);
    gload16(ag1, sa1);
    gload16(bg0, sb0);
    gload16(bg1, sb1);
    __syncthreads();

    f16x8 af[4], bfr[4];
#pragma unroll
    for (int t = 0; t < 4; ++t)
      af[t] = *(const f16x8*)(smem + (wm + t * 16 + l16) * 64 + qoff);
#pragma unroll
    for (int t = 0; t < 4; ++t)
      bfr[t] = *(const f16x8*)(smem + 8192 + (wn + t * 16 + l16) * 64 + qoff);
#pragma unroll
    for (int mt = 0; mt < 4; ++mt)
#pragma unroll
      for (int nt = 0; nt < 4; ++nt)
        acc[mt][nt] = __builtin_amdgcn_mfma_f32_16x16x32_f16(af[mt], bfr[nt], acc[mt][nt], 0, 0, 0);
    __syncthreads();

    ag0 += BK; ag1 += BK; bg0 += BK; bg1 += BK;
  }

  // epilogue: C/D col=lane&15, row=quad*4+reg; scatter to out[token], +bias
#pragma unroll
  for (int mt = 0; mt < 4; ++mt) {
    const int rowb = m0 + wm + mt * 16 + quad * 4;
    int tk[4];
#pragma unroll
    for (int r = 0; r < 4; ++r) tk[r] = inv[rowb + r];
#pragma unroll
    for (int nt = 0; nt < 4; ++nt) {
      const int col = n0 + wn + nt * 16 + l16;
      const float bv = bias[col];
#pragma unroll
      for (int r = 0; r < 4; ++r) {
        if (tk[r] >= 0)
          out[(size_t)tk[r] * NOUT + col] = acc[mt][nt][r] + bv;
      }
    }
  }
}

// ================= kernel 2 (fallback, ws too small): in-loop dequant =================
__global__ __launch_bounds__(256) void kdq(
    const _Float16* __restrict__ xh, const _Float16* __restrict__ wbh,
    const int* __restrict__ qw0, const int* __restrict__ qw1,
    const int* __restrict__ qz0, const int* __restrict__ qz1,
    const float* __restrict__ sc0, const float* __restrict__ sc1,
    const float* __restrict__ bias,
    const int* __restrict__ inv, const int* __restrict__ meta,
    float* __restrict__ out)
{
  const int m0 = blockIdx.y * BM;
  if (m0 >= meta[4]) return;
  int ad = 0;
  if (m0 >= meta[1]) ad = 1;
  if (m0 >= meta[2]) ad = 2;
  if (m0 >= meta[3]) ad = 3;
  if (m0 >= meta[5 + ad]) return;

  const int n0 = blockIdx.x * BN;
  const int sl = n0 >> 12;
  const int tid  = threadIdx.x;
  const int wave = tid >> 6;
  const int lane = tid & 63;
  const int quad = lane >> 4;
  const int l16  = lane & 15;
  const int wm = (wave & 1) << 6;
  const int wn = (wave >> 1) << 6;

  __shared__ __align__(16) char smem[16384];

  f32x4 acc[4][4];
#pragma unroll
  for (int i = 0; i < 4; ++i)
#pragma unroll
    for (int j = 0; j < 4; ++j) acc[i][j] = (f32x4)0.0f;

  const int kch = (((tid & 3) ^ ((tid >> 3) & 3)) << 3);
  const int rloc = tid >> 2;
  int r0 = inv[m0 + rloc];       if (r0 < 0) r0 = T_TOK;
  int r1 = inv[m0 + rloc + 64];  if (r1 < 0) r1 = T_TOK;
  const _Float16* ag0 = xh + (size_t)r0 * DIN + kch;
  const _Float16* ag1 = xh + (size_t)r1 * DIN + kch;
  char* sa0 = smem + wave * 1024;
  char* sa1 = smem + 4096 + wave * 1024;

  const int o_local = tid >> 1;
  const int o = n0 + o_local;
  const int o_sl = o & (OSL - 1);
  const int* qw = (sl ? qw1 : qw0) + ((size_t)ad * OSL + o_sl) * (DIN / 8) + ((tid & 1) << 1);
  const int zw = (sl ? qz1 : qz0)[ad * (OSL / 8) + (o_sl >> 3)];
  const float s = (sl ? sc1 : sc0)[(size_t)ad * OSL + o_sl];
  const int z = (zw >> ((o_sl & 7) << 2)) & 0xF;
  f16x2 s2; s2[0] = s2[1] = (_Float16)s;
  f16x2 k2; k2[0] = k2[1] = (_Float16)(float)(-(1024 + z));
  const _Float16* wbhp = wbh + (size_t)o * DIN + ((tid & 1) << 4);

  const int bswz = (o_local >> 1) & 3;
  char* bb = smem + 8192 + o_local * 64;
  char* bw0 = bb + (((((tid & 1) << 1)    ) ^ bswz) << 4);
  char* bw1 = bb + (((((tid & 1) << 1) | 1) ^ bswz) << 4);
  const int qoff = ((quad ^ ((l16 >> 1) & 3)) << 4);

  for (int k0 = 0; k0 < DIN; k0 += BK) {
    gload16(ag0, sa0);
    gload16(ag1, sa1);
    int2 wv = *(const int2*)qw;
    union { f16x8 v; f16x2 p[4]; } wA, wB;
    wA.v = *(const f16x8*)wbhp;
    wB.v = *(const f16x8*)(wbhp + 8);
    const uint32_t wx = (uint32_t)wv.x, wy = (uint32_t)wv.y;
    union { f16x8 v; f16x2 p[4]; } h0, h1;
#pragma unroll
    for (int j = 0; j < 4; ++j) {
      uint32_t t0 = ((wx >> (4 * j)) & 0x000F000Fu) | 0x64006400u;
      uint32_t t1 = ((wy >> (4 * j)) & 0x000F000Fu) | 0x64006400u;
      h0.p[j] = (u2h(t0) + k2) * s2 + wA.p[j];
      h1.p[j] = (u2h(t1) + k2) * s2 + wB.p[j];
    }
    *(f16x8*)bw0 = h0.v;
    *(f16x8*)bw1 = h1.v;
    __syncthreads();

    f16x8 af[4], bfr[4];
#pragma unroll
    for (int t = 0; t < 4; ++t)
      af[t] = *(const f16x8*)(smem + (wm + t * 16 + l16) * 64 + qoff);
#pragma unroll
    for (int t = 0; t < 4; ++t)
      bfr[t] = *(const f16x8*)(smem + 8192 + (wn + t * 16 + l16) * 64 + qoff);
#pragma unroll
    for (int mt = 0; mt < 4; ++mt)
#pragma unroll
      for (int nt = 0; nt < 4; ++nt)
        acc[mt][nt] = __builtin_amdgcn_mfma_f32_16x16x32_f16(af[mt], bfr[nt], acc[mt][nt], 0, 0, 0);
    __syncthreads();

    ag0 += BK; ag1 += BK; qw += 4; wbhp += BK;
  }

#pragma unroll
  for (int mt = 0; mt < 4; ++mt) {
    const int rowb = m0 + wm + mt * 16 + quad * 4;
    int tk[4];
#pragma unroll
    for (int r = 0; r < 4; ++r) tk[r] = inv[rowb + r];
#pragma unroll
    for (int nt = 0; nt < 4; ++nt) {
      const int col = n0 + wn + nt * 16 + l16;
      const float bv = bias[col];
#pragma unroll
      for (int r = 0; r < 4; ++r) {
        if (tk[r] >= 0)
          out[(size_t)tk[r] * NOUT + col] = acc[mt][nt][r] + bv;
      }
    }
  }
}

extern "C" void kernel_launch(void* const* d_in, const int* in_sizes, int n_in,
                              void* d_out, int out_size, void* d_ws, size_t ws_size,
                              hipStream_t stream) {
  const float* x    = (const float*)d_in[0];
  const float* wb   = (const float*)d_in[1];
  const float* bias = (const float*)d_in[2];
  const int*   qw0  = (const int*)d_in[3];
  const int*   qw1  = (const int*)d_in[4];
  const int*   qz0  = (const int*)d_in[5];
  const int*   qz1  = (const int*)d_in[6];
  const float* sc0  = (const float*)d_in[7];
  const float* sc1  = (const float*)d_in[8];
  const int*   indices = (const int*)d_in[11];
  float* out = (float*)d_out;

  // workspace: xh [(T_TOK+1)*DIN f16] | inv | meta | weff (128 MB) or wbh (32 MB)
  char* w = (char*)d_ws;
  _Float16* xh = (_Float16*)w;
  size_t off = (size_t)(T_TOK + 1) * DIN * 2;
  int* inv  = (int*)(w + off);
  int* meta = inv + ROWS_PAD;
  size_t woff = (off + (size_t)ROWS_PAD * 4 + 64 + 255) & ~(size_t)255;
  _Float16* wout = (_Float16*)(w + woff);
  const bool full = ws_size >= woff + (size_t)4 * NOUT * DIN * 2;

  const int nprep = 2 + T_TOK + NOUT;   // sort + x rows (+zero) + weight rows
  dim3 g(NOUT / BN, ROWS_PAD / BM, 1);  // 64 x 11

  if (full) {
    prep_all<true><<<nprep, 256, 0, stream>>>(x, wb, qw0, qw1, qz0, qz1, sc0, sc1,
                                              indices, xh, wout, inv, meta);
    kslim<<<g, 256, 0, stream>>>(xh, wout, bias, inv, meta, out);
  } else {
    prep_all<false><<<nprep, 256, 0, stream>>>(x, wb, qw0, qw1, qz0, qz1, sc0, sc1,
                                               indices, xh, wout, inv, meta);
    kdq<<<g, 256, 0, stream>>>(xh, wout, qw0, qw1, qz0, qz1, sc0, sc1,
                               bias, inv, meta, out);
  }
}